// Round 3
// baseline (1025.336 us; speedup 1.0000x reference)
//
#include <hip/hip_runtime.h>
#include <hip/hip_bf16.h>

// ConvNetLayer fused pipeline, MI355X (gfx950). Round 3.
//
// Column-split GEMM waves (wave = 32-col n-group, ~116 regs -> 4 waves/SIMD)
// + permuted intermediate column layout so every lane's epilogue is 2x16B
// contiguous (no HBM write amplification, vectorized gathers).
//
// Permutation (within each 32-col group): stored index p = khalf*16 + g*4 + j
// for true offset t = g*8 + khalf*4 + j.  All ws intermediates use it; it is
// undone in k_bond_out / k_atom_out / bn_stats' gamma-beta load.

#define H   128
#define NA  300000
#define NB  600000
#define EPS 1e-5f

#define NTILE_A (NA / 32)   // 9375
#define NTILE_B (NB / 32)   // 18750
#define GRID_GEMM 1024
#define EGRID 2048

typedef __attribute__((ext_vector_type(4)))  float  f32x4;
typedef __attribute__((ext_vector_type(16))) float  f32x16;
typedef __attribute__((ext_vector_type(8)))  __bf16 bfv8;
typedef __attribute__((ext_vector_type(8)))  unsigned short u16x8;

static __device__ __forceinline__ unsigned short f2bf(float f) {
    unsigned u = __float_as_uint(f);
    u = (u + 0x7fffu + ((u >> 16) & 1u)) >> 16;   // RNE
    return (unsigned short)u;
}
static __device__ __forceinline__ float bf2f(unsigned short s) {
    return __uint_as_float(((unsigned)s) << 16);
}

// f32 row chunk -> bf16 MFMA fragment (8 elems: lane holds [k*16 + khalf*8 + i])
static __device__ __forceinline__ bfv8 load_frag(const float* __restrict__ p) {
    f32x4 a0 = *(const f32x4*)p;
    f32x4 a1 = *(const f32x4*)(p + 4);
    bfv8 f;
#pragma unroll
    for (int i = 0; i < 4; i++) { f[i] = (__bf16)a0[i]; f[i + 4] = (__bf16)a1[i]; }
    return f;
}

// ---------------- Kernel A: Ux,Vx,Bx,Cx = lin(X,{U,V,B,C}) bf16 (permuted) ---
// 4 waves/block; wave = n-group; loops over the 4 weights per tile (frags
// reloaded from L1/L2); persistent over atom tiles.
__global__ __launch_bounds__(256, 4) void k_atom_gemm(
    const float* __restrict__ X,
    const float* __restrict__ Uw, const float* __restrict__ Ub,
    const float* __restrict__ Vw, const float* __restrict__ Vb,
    const float* __restrict__ Bw, const float* __restrict__ Bb,
    const float* __restrict__ Cw, const float* __restrict__ Cb,
    unsigned short* __restrict__ Uxo, unsigned short* __restrict__ Vxo,
    unsigned short* __restrict__ Bxo, unsigned short* __restrict__ Cxo)
{
    const int lane  = threadIdx.x & 63;
    const int ng    = threadIdx.x >> 6;     // n-group (32 output cols)
    const int l31   = lane & 31;
    const int khalf = lane >> 5;

    const int wrow_off = (ng * 32 + l31) * H + khalf * 8;  // weight frag base
    const int cperm    = ng * 32 + khalf * 16;             // permuted store base
    const int cbias    = ng * 32 + khalf * 4;              // true bias base

#pragma unroll 1
    for (int t = blockIdx.x; t < NTILE_A; t += gridDim.x) {
        const int row = t * 32 + l31;
        const float* xp = X + (size_t)row * H + khalf * 8;
        bfv8 xf[8];
#pragma unroll
        for (int k = 0; k < 8; k++) xf[k] = load_frag(xp + k * 16);

#pragma unroll 1
        for (int wt = 0; wt < 4; wt++) {
            const float* Wpp; const float* bpp; unsigned short* Opp;
            if (wt == 0)      { Wpp = Uw; bpp = Ub; Opp = Uxo; }
            else if (wt == 1) { Wpp = Vw; bpp = Vb; Opp = Vxo; }
            else if (wt == 2) { Wpp = Bw; bpp = Bb; Opp = Bxo; }
            else              { Wpp = Cw; bpp = Cb; Opp = Cxo; }

            const float* wr = Wpp + wrow_off;
            bfv8 aw[8];
#pragma unroll
            for (int k = 0; k < 8; k++) aw[k] = load_frag(wr + k * 16);

            f32x16 acc;
#pragma unroll
            for (int i = 0; i < 16; i++) acc[i] = 0.0f;
#pragma unroll
            for (int k = 0; k < 8; k++)
                acc = __builtin_amdgcn_mfma_f32_32x32x16_bf16(aw[k], xf[k], acc, 0, 0, 0);

            f32x4 bv[4];
#pragma unroll
            for (int g = 0; g < 4; g++) bv[g] = *(const f32x4*)(bpp + cbias + g * 8);

            // acc[v] (v = g*4+j) -> permuted col cperm + v : contiguous 32B
            u16x8 o0, o1;
#pragma unroll
            for (int v = 0; v < 8; v++) {
                o0[v] = f2bf(acc[v]     + bv[v >> 2][v & 3]);
                o1[v] = f2bf(acc[v + 8] + bv[2 + (v >> 2)][v & 3]);
            }
            unsigned short* op = Opp + (size_t)row * H + cperm;
            *(u16x8*)op       = o0;
            *(u16x8*)(op + 8) = o1;
        }
    }
}

// ------------- Kernel B: esyn = A*bond + Ab + Bx[g0] + Cx[g1]  (bf16, perm) --
__global__ __launch_bounds__(256, 4) void k_bond_gemm(
    const float* __restrict__ Xb,
    const float* __restrict__ Aw, const float* __restrict__ Ab,
    const int* __restrict__ g2,
    const unsigned short* __restrict__ Bx, const unsigned short* __restrict__ Cx,
    unsigned short* __restrict__ esyn)
{
    const int lane  = threadIdx.x & 63;
    const int ng    = threadIdx.x >> 6;
    const int l31   = lane & 31;
    const int khalf = lane >> 5;

    const int cperm = ng * 32 + khalf * 16;
    const int cbias = ng * 32 + khalf * 4;

    // resident weight frags + bias (permuted order)
    bfv8 aw[8];
    const float* wr = Aw + (ng * 32 + l31) * H + khalf * 8;
#pragma unroll
    for (int k = 0; k < 8; k++) aw[k] = load_frag(wr + k * 16);
    f32x4 bv[4];
#pragma unroll
    for (int g = 0; g < 4; g++) bv[g] = *(const f32x4*)(Ab + cbias + g * 8);

#pragma unroll 1
    for (int t = blockIdx.x; t < NTILE_B; t += gridDim.x) {
        const int e = t * 32 + l31;
        const float* xp = Xb + (size_t)e * H + khalf * 8;

        bfv8 xf[8];
#pragma unroll
        for (int k = 0; k < 8; k++) xf[k] = load_frag(xp + k * 16);

        // issue gathers before the MFMA chain (latency hidden under MFMA)
        const int2 gg = *(const int2*)(g2 + 2 * (size_t)e);
        const unsigned short* bxp = Bx + (size_t)gg.x * H + cperm;
        const unsigned short* cxp = Cx + (size_t)gg.y * H + cperm;
        u16x8 b0 = *(const u16x8*)bxp, b1 = *(const u16x8*)(bxp + 8);
        u16x8 c0 = *(const u16x8*)cxp, c1 = *(const u16x8*)(cxp + 8);

        f32x16 acc;
#pragma unroll
        for (int i = 0; i < 16; i++) acc[i] = 0.0f;
#pragma unroll
        for (int k = 0; k < 8; k++)
            acc = __builtin_amdgcn_mfma_f32_32x32x16_bf16(aw[k], xf[k], acc, 0, 0, 0);

        u16x8 o0, o1;
#pragma unroll
        for (int v = 0; v < 8; v++) {
            o0[v] = f2bf(acc[v]     + bv[v >> 2][v & 3]       + bf2f(b0[v]) + bf2f(c0[v]));
            o1[v] = f2bf(acc[v + 8] + bv[2 + (v >> 2)][v & 3] + bf2f(b1[v]) + bf2f(c1[v]));
        }
        unsigned short* op = esyn + (size_t)e * H + cperm;
        *(u16x8*)op       = o0;
        *(u16x8*)(op + 8) = o1;
    }
}

// ------------- Kernel D1: per-block per-column partial sums (permuted cols) --
__global__ __launch_bounds__(256) void k_col_stats(const unsigned short* __restrict__ buf,
                                                   long nrows,
                                                   float* __restrict__ psum,
                                                   float* __restrict__ psq)
{
    const size_t total  = (size_t)nrows * (H / 8);
    const size_t stride = (size_t)gridDim.x * 256;     // multiple of 16
    float s[8], q[8];
#pragma unroll
    for (int j = 0; j < 8; j++) { s[j] = 0.f; q[j] = 0.f; }
    for (size_t i = (size_t)blockIdx.x * 256 + threadIdx.x; i < total; i += stride) {
        u16x8 v = ((const u16x8*)buf)[i];
#pragma unroll
        for (int j = 0; j < 8; j++) { float f = bf2f(v[j]); s[j] += f; q[j] += f * f; }
    }
    __shared__ float ls[256][8], lq[256][8];
#pragma unroll
    for (int j = 0; j < 8; j++) { ls[threadIdx.x][j] = s[j]; lq[threadIdx.x][j] = q[j]; }
    __syncthreads();
    if (threadIdx.x < 128) {
        const int c = threadIdx.x, cg = c >> 3, j = c & 7;
        float S = 0.f, Q = 0.f;
        for (int rg = 0; rg < 16; rg++) { S += ls[rg * 16 + cg][j]; Q += lq[rg * 16 + cg][j]; }
        psum[(size_t)blockIdx.x * H + c] = S;
        psq [(size_t)blockIdx.x * H + c] = Q;
    }
}

// ---------------- Kernel C: reduce partials -> scale/shift (permuted index) --
__global__ void k_bn_stats(const float* __restrict__ psum, const float* __restrict__ psq,
                           int nblk, float invN,
                           const float* __restrict__ gamma, const float* __restrict__ beta,
                           float* __restrict__ scale, float* __restrict__ shift)
{
    __shared__ float ls[256], lq[256];
    const int c = blockIdx.x;                 // permuted column index
    float s = 0.f, q = 0.f;
    for (int i = threadIdx.x; i < nblk; i += 256) {
        s += psum[(size_t)i * H + c];
        q += psq [(size_t)i * H + c];
    }
    ls[threadIdx.x] = s; lq[threadIdx.x] = q;
    __syncthreads();
    for (int off = 128; off > 0; off >>= 1) {
        if ((int)threadIdx.x < off) {
            ls[threadIdx.x] += ls[threadIdx.x + off];
            lq[threadIdx.x] += lq[threadIdx.x + off];
        }
        __syncthreads();
    }
    if (threadIdx.x == 0) {
        // permuted -> true column for gamma/beta
        const int r = c & 31, kh = r >> 4, wi = r & 15;
        const int ct = (c & ~31) + (wi >> 2) * 8 + kh * 4 + (wi & 3);
        float mean = ls[0] * invN;
        float var  = lq[0] * invN - mean * mean;
        float sc   = gamma[ct] * rsqrtf(var + EPS);
        scale[c] = sc;
        shift[c] = beta[ct] - mean * sc;
    }
}

// ---------------- Kernel D2: bond finalize  esyn(bf16,perm) -> f32 true ------
__global__ __launch_bounds__(256) void k_bond_out(const unsigned short* __restrict__ esyn,
                                                  float* __restrict__ y,
                                                  const float* __restrict__ scale,
                                                  const float* __restrict__ shift)
{
    const size_t total  = (size_t)NB * (H / 8);
    const size_t stride = (size_t)gridDim.x * 256;     // multiple of 16
    const int c0 = (threadIdx.x & 15) * 8;             // permuted chunk base
    const f32x4 sc0 = *(const f32x4*)(scale + c0), sc1 = *(const f32x4*)(scale + c0 + 4);
    const f32x4 sh0 = *(const f32x4*)(shift + c0), sh1 = *(const f32x4*)(shift + c0 + 4);
    // true column chunks for this permuted chunk
    const int tc0 = (c0 & ~31) + (((c0 >> 2) & 3) * 8) + ((c0 >> 4) & 1) * 4;
    const int tc1 = tc0 + 8;
    for (size_t i = (size_t)blockIdx.x * 256 + threadIdx.x; i < total; i += stride) {
        u16x8 v = ((const u16x8*)esyn)[i];
        const size_t row = i >> 4;
        f32x4 o0, o1;
#pragma unroll
        for (int j = 0; j < 4; j++) {
            o0[j] = fmaxf(bf2f(v[j])     * sc0[j] + sh0[j], 0.0f);
            o1[j] = fmaxf(bf2f(v[j + 4]) * sc1[j] + sh1[j], 0.0f);
        }
        float* yp = y + row * H;
        *(f32x4*)(yp + tc0) = o0;
        *(f32x4*)(yp + tc1) = o1;
    }
}

// -------- Kernel E: syn_a = Ux + sum_k sigmoid(esyn[b])*Vx[a]  (bf16, perm) --
__global__ __launch_bounds__(256) void k_atom_msg(
    const unsigned short* __restrict__ Ux,
    const unsigned short* __restrict__ Vx,
    const unsigned short* __restrict__ esyn,
    const int* __restrict__ adj,
    const int* __restrict__ abadj,
    unsigned short* __restrict__ syn_a,
    float* __restrict__ psum, float* __restrict__ psq)
{
    const int cg = threadIdx.x & 15;
    const int rh = threadIdx.x >> 4;
    const int c0 = cg * 8;
    float s[8], q[8];
#pragma unroll
    for (int j = 0; j < 8; j++) { s[j] = 0.f; q[j] = 0.f; }

    for (int r0 = blockIdx.x * 16; r0 < NA; r0 += gridDim.x * 16) {
        const int r = r0 + rh;
        u16x8 uv = *(const u16x8*)(Ux + (size_t)r * H + c0);
        float v[8];
#pragma unroll
        for (int j = 0; j < 8; j++) v[j] = bf2f(uv[j]);
#pragma unroll
        for (int k = 0; k < 6; k++) {
            const int a = adj[r * 6 + k];
            const int b = abadj[r * 6 + k];
            u16x8 vx = *(const u16x8*)(Vx   + (size_t)a * H + c0);
            u16x8 es = *(const u16x8*)(esyn + (size_t)b * H + c0);
#pragma unroll
            for (int j = 0; j < 8; j++) {
                float g = 1.0f / (1.0f + __expf(-bf2f(es[j])));
                v[j] += g * bf2f(vx[j]);
            }
        }
        u16x8 ov;
#pragma unroll
        for (int j = 0; j < 8; j++) ov[j] = f2bf(v[j]);
        *(u16x8*)(syn_a + (size_t)r * H + c0) = ov;
#pragma unroll
        for (int j = 0; j < 8; j++) { s[j] += v[j]; q[j] += v[j] * v[j]; }
    }

    __shared__ float ls[256][8], lq[256][8];
#pragma unroll
    for (int j = 0; j < 8; j++) { ls[threadIdx.x][j] = s[j]; lq[threadIdx.x][j] = q[j]; }
    __syncthreads();
    if (threadIdx.x < 128) {
        const int c = threadIdx.x, g = c >> 3, j = c & 7;
        float S = 0.f, Q = 0.f;
        for (int rg = 0; rg < 16; rg++) { S += ls[rg * 16 + g][j]; Q += lq[rg * 16 + g][j]; }
        psum[(size_t)blockIdx.x * H + c] = S;
        psq [(size_t)blockIdx.x * H + c] = Q;
    }
}

// ---------------- Kernel F: atom finalize: bn(syn_a)+relu + residual ---------
__global__ __launch_bounds__(256) void k_atom_out(const unsigned short* __restrict__ syn,
                                                  const float* __restrict__ xin,
                                                  float* __restrict__ y,
                                                  const float* __restrict__ scale,
                                                  const float* __restrict__ shift)
{
    const size_t total  = (size_t)NA * (H / 8);
    const size_t stride = (size_t)gridDim.x * 256;     // multiple of 16
    const int c0 = (threadIdx.x & 15) * 8;
    const f32x4 sc0 = *(const f32x4*)(scale + c0), sc1 = *(const f32x4*)(scale + c0 + 4);
    const f32x4 sh0 = *(const f32x4*)(shift + c0), sh1 = *(const f32x4*)(shift + c0 + 4);
    const int tc0 = (c0 & ~31) + (((c0 >> 2) & 3) * 8) + ((c0 >> 4) & 1) * 4;
    const int tc1 = tc0 + 8;
    for (size_t i = (size_t)blockIdx.x * 256 + threadIdx.x; i < total; i += stride) {
        u16x8 v = ((const u16x8*)syn)[i];
        const size_t row = i >> 4;
        const float* xp = xin + row * H;
        f32x4 x0 = *(const f32x4*)(xp + tc0), x1 = *(const f32x4*)(xp + tc1);
        f32x4 o0, o1;
#pragma unroll
        for (int j = 0; j < 4; j++) {
            o0[j] = fmaxf(bf2f(v[j])     * sc0[j] + sh0[j], 0.0f) + x0[j];
            o1[j] = fmaxf(bf2f(v[j + 4]) * sc1[j] + sh1[j], 0.0f) + x1[j];
        }
        float* yp = y + row * H;
        *(f32x4*)(yp + tc0) = o0;
        *(f32x4*)(yp + tc1) = o1;
    }
}

extern "C" void kernel_launch(void* const* d_in, const int* in_sizes, int n_in,
                              void* d_out, int out_size, void* d_ws, size_t ws_size,
                              hipStream_t stream)
{
    const float* X     = (const float*)d_in[0];
    const float* Xb    = (const float*)d_in[1];
    const int*   adj   = (const int*)d_in[2];
    const int*   abadj = (const int*)d_in[3];
    const int*   g2    = (const int*)d_in[4];
    const float* Uw = (const float*)d_in[5],  *Ub = (const float*)d_in[6];
    const float* Vw = (const float*)d_in[7],  *Vb = (const float*)d_in[8];
    const float* Aw = (const float*)d_in[9],  *Ab = (const float*)d_in[10];
    const float* Bw = (const float*)d_in[11], *Bb = (const float*)d_in[12];
    const float* Cw = (const float*)d_in[13], *Cb = (const float*)d_in[14];
    const float* gb = (const float*)d_in[15], *bb = (const float*)d_in[16];
    const float* ga = (const float*)d_in[17], *ba = (const float*)d_in[18];

    float* out_atom = (float*)d_out;
    float* out_bond = out_atom + (size_t)NA * H;

    char* ws = (char*)d_ws;
    size_t o = 0;
    unsigned short* Ux    = (unsigned short*)(ws + o); o += (size_t)NA * H * 2;
    unsigned short* Vx    = (unsigned short*)(ws + o); o += (size_t)NA * H * 2;
    unsigned short* Bx    = (unsigned short*)(ws + o); o += (size_t)NA * H * 2;
    unsigned short* Cx    = (unsigned short*)(ws + o); o += (size_t)NA * H * 2;
    unsigned short* esyn  = (unsigned short*)(ws + o); o += (size_t)NB * H * 2;
    unsigned short* syn_a = (unsigned short*)(ws + o); o += (size_t)NA * H * 2;
    float* psum_b = (float*)(ws + o);  o += (size_t)EGRID * H * 4;
    float* psq_b  = (float*)(ws + o);  o += (size_t)EGRID * H * 4;
    float* psum_a = (float*)(ws + o);  o += (size_t)EGRID * H * 4;
    float* psq_a  = (float*)(ws + o);  o += (size_t)EGRID * H * 4;
    float* scale_b = (float*)(ws + o); o += 512;
    float* shift_b = (float*)(ws + o); o += 512;
    float* scale_a = (float*)(ws + o); o += 512;
    float* shift_a = (float*)(ws + o); o += 512;
    (void)o; (void)ws_size; (void)in_sizes; (void)n_in; (void)out_size;

    k_atom_gemm<<<GRID_GEMM, 256, 0, stream>>>(X, Uw, Ub, Vw, Vb, Bw, Bb, Cw, Cb,
                                               Ux, Vx, Bx, Cx);
    k_bond_gemm<<<GRID_GEMM, 256, 0, stream>>>(Xb, Aw, Ab, g2, Bx, Cx, esyn);
    k_col_stats<<<EGRID, 256, 0, stream>>>(esyn, NB, psum_b, psq_b);
    k_bn_stats<<<H, 256, 0, stream>>>(psum_b, psq_b, EGRID, 1.0f / NB, gb, bb, scale_b, shift_b);
    k_bond_out<<<EGRID, 256, 0, stream>>>(esyn, out_bond, scale_b, shift_b);
    k_atom_msg<<<EGRID, 256, 0, stream>>>(Ux, Vx, esyn, adj, abadj, syn_a, psum_a, psq_a);
    k_bn_stats<<<H, 256, 0, stream>>>(psum_a, psq_a, EGRID, 1.0f / NA, ga, ba, scale_a, shift_a);
    k_atom_out<<<EGRID, 256, 0, stream>>>(syn_a, X, out_atom, scale_a, shift_a);
}

// Round 4
// 859.695 us; speedup vs baseline: 1.1927x; 1.1927x over previous
//
#include <hip/hip_runtime.h>
#include <hip/hip_bf16.h>

// ConvNetLayer fused pipeline, MI355X (gfx950). Round 4.
//
// k_atom_gemm: all-4-weight register residency (32 frags/wave for its n-group,
// loaded once per persistent block) + next-tile X prefetch. No biases in
// atom_gemm: Bb+Cb folded into bond_gemm's resident bias (with Ab), Ub/Vb
// added in k_atom_msg. Permuted intermediate layout as R3 (contiguous 32B
// per-lane epilogue): stored p = khalf*16 + g*4 + j for true t = g*8+khalf*4+j.

#define H   128
#define NA  300000
#define NB  600000
#define EPS 1e-5f

#define NTILE_A (NA / 32)   // 9375
#define NTILE_B (NB / 32)   // 18750
#define GRID_A  512
#define GRID_B  1024
#define EGRID   2048

typedef __attribute__((ext_vector_type(4)))  float  f32x4;
typedef __attribute__((ext_vector_type(16))) float  f32x16;
typedef __attribute__((ext_vector_type(8)))  __bf16 bfv8;
typedef __attribute__((ext_vector_type(8)))  unsigned short u16x8;

static __device__ __forceinline__ unsigned short f2bf(float f) {
    unsigned u = __float_as_uint(f);
    u = (u + 0x7fffu + ((u >> 16) & 1u)) >> 16;   // RNE
    return (unsigned short)u;
}
static __device__ __forceinline__ float bf2f(unsigned short s) {
    return __uint_as_float(((unsigned)s) << 16);
}

static __device__ __forceinline__ bfv8 cvt2(f32x4 a, f32x4 b) {
    bfv8 f;
#pragma unroll
    for (int i = 0; i < 4; i++) { f[i] = (__bf16)a[i]; f[i + 4] = (__bf16)b[i]; }
    return f;
}

// f32 row chunk -> bf16 MFMA fragment (lane holds [k*16 + khalf*8 + i])
static __device__ __forceinline__ bfv8 load_frag(const float* __restrict__ p) {
    return cvt2(*(const f32x4*)p, *(const f32x4*)(p + 4));
}

// ---------------- Kernel A: Ux,Vx,Bx,Cx = X*{U,V,B,C}^T bf16 (perm, NO bias) -
// 4 waves/block, wave = n-group; all 4 weights resident; X prefetched.
__global__ __launch_bounds__(256, 2) void k_atom_gemm(
    const float* __restrict__ X,
    const float* __restrict__ Uw, const float* __restrict__ Vw,
    const float* __restrict__ Bw, const float* __restrict__ Cw,
    unsigned short* __restrict__ Uxo, unsigned short* __restrict__ Vxo,
    unsigned short* __restrict__ Bxo, unsigned short* __restrict__ Cxo)
{
    const int lane  = threadIdx.x & 63;
    const int ng    = threadIdx.x >> 6;
    const int l31   = lane & 31;
    const int khalf = lane >> 5;

    const int wrow_off = (ng * 32 + l31) * H + khalf * 8;
    const int cperm    = ng * 32 + khalf * 16;

    // resident weight fragments: 4 weights x 8 frags = 128 VGPR
    bfv8 aw0[8], aw1[8], aw2[8], aw3[8];
#pragma unroll
    for (int k = 0; k < 8; k++) {
        aw0[k] = load_frag(Uw + wrow_off + k * 16);
        aw1[k] = load_frag(Vw + wrow_off + k * 16);
        aw2[k] = load_frag(Bw + wrow_off + k * 16);
        aw3[k] = load_frag(Cw + wrow_off + k * 16);
    }

    int t = blockIdx.x;
    const int stride = gridDim.x;

    f32x4 xr[16];
    {
        const float* xp = X + (size_t)(t * 32 + l31) * H + khalf * 8;
#pragma unroll
        for (int k = 0; k < 8; k++) {
            xr[2 * k]     = *(const f32x4*)(xp + k * 16);
            xr[2 * k + 1] = *(const f32x4*)(xp + k * 16 + 4);
        }
    }

#pragma unroll 1
    for (; t < NTILE_A; ) {
        const int tn = t + stride;

        bfv8 xf[8];
#pragma unroll
        for (int k = 0; k < 8; k++) xf[k] = cvt2(xr[2 * k], xr[2 * k + 1]);

        // prefetch next tile (clamped; overlaps MFMA + stores below)
        {
            const int tl = (tn < NTILE_A) ? tn : t;
            const float* xp = X + (size_t)(tl * 32 + l31) * H + khalf * 8;
#pragma unroll
            for (int k = 0; k < 8; k++) {
                xr[2 * k]     = *(const f32x4*)(xp + k * 16);
                xr[2 * k + 1] = *(const f32x4*)(xp + k * 16 + 4);
            }
        }

        const size_t obase = (size_t)(t * 32 + l31) * H + cperm;

#define DO_WT(AW, OP)                                                          \
        {                                                                      \
            f32x16 acc;                                                        \
            _Pragma("unroll") for (int i = 0; i < 16; i++) acc[i] = 0.0f;      \
            _Pragma("unroll") for (int k = 0; k < 8; k++)                      \
                acc = __builtin_amdgcn_mfma_f32_32x32x16_bf16(AW[k], xf[k], acc, 0, 0, 0); \
            u16x8 o0, o1;                                                      \
            _Pragma("unroll") for (int v = 0; v < 8; v++) {                    \
                o0[v] = f2bf(acc[v]); o1[v] = f2bf(acc[v + 8]);                \
            }                                                                  \
            *(u16x8*)(OP + obase)     = o0;                                    \
            *(u16x8*)(OP + obase + 8) = o1;                                    \
        }
        DO_WT(aw0, Uxo)
        DO_WT(aw1, Vxo)
        DO_WT(aw2, Bxo)
        DO_WT(aw3, Cxo)
#undef DO_WT
        t = tn;
    }
}

// ------------- Kernel B: esyn = A*xb + (Ab+Bb+Cb) + Bx[g0] + Cx[g1] (bf16) ---
__global__ __launch_bounds__(256, 4) void k_bond_gemm(
    const float* __restrict__ Xb,
    const float* __restrict__ Aw, const float* __restrict__ Ab,
    const float* __restrict__ Bb, const float* __restrict__ Cb,
    const int* __restrict__ g2,
    const unsigned short* __restrict__ Bx, const unsigned short* __restrict__ Cx,
    unsigned short* __restrict__ esyn)
{
    const int lane  = threadIdx.x & 63;
    const int ng    = threadIdx.x >> 6;
    const int l31   = lane & 31;
    const int khalf = lane >> 5;

    const int cperm = ng * 32 + khalf * 16;
    const int cbias = ng * 32 + khalf * 4;

    bfv8 aw[8];
    const float* wr = Aw + (ng * 32 + l31) * H + khalf * 8;
#pragma unroll
    for (int k = 0; k < 8; k++) aw[k] = load_frag(wr + k * 16);

    // combined bias Ab+Bb+Cb (true-col layout, matching acc order)
    f32x4 bv[4];
#pragma unroll
    for (int g = 0; g < 4; g++) {
        f32x4 a = *(const f32x4*)(Ab + cbias + g * 8);
        f32x4 b = *(const f32x4*)(Bb + cbias + g * 8);
        f32x4 c = *(const f32x4*)(Cb + cbias + g * 8);
#pragma unroll
        for (int j = 0; j < 4; j++) a[j] += b[j] + c[j];
        bv[g] = a;
    }

#pragma unroll 1
    for (int t = blockIdx.x; t < NTILE_B; t += gridDim.x) {
        const int e = t * 32 + l31;
        const float* xp = Xb + (size_t)e * H + khalf * 8;

        bfv8 xf[8];
#pragma unroll
        for (int k = 0; k < 8; k++) xf[k] = load_frag(xp + k * 16);

        const int2 gg = *(const int2*)(g2 + 2 * (size_t)e);
        const unsigned short* bxp = Bx + (size_t)gg.x * H + cperm;
        const unsigned short* cxp = Cx + (size_t)gg.y * H + cperm;
        u16x8 b0 = *(const u16x8*)bxp, b1 = *(const u16x8*)(bxp + 8);
        u16x8 c0 = *(const u16x8*)cxp, c1 = *(const u16x8*)(cxp + 8);

        f32x16 acc;
#pragma unroll
        for (int i = 0; i < 16; i++) acc[i] = 0.0f;
#pragma unroll
        for (int k = 0; k < 8; k++)
            acc = __builtin_amdgcn_mfma_f32_32x32x16_bf16(aw[k], xf[k], acc, 0, 0, 0);

        u16x8 o0, o1;
#pragma unroll
        for (int v = 0; v < 8; v++) {
            o0[v] = f2bf(acc[v]     + bv[v >> 2][v & 3]       + bf2f(b0[v]) + bf2f(c0[v]));
            o1[v] = f2bf(acc[v + 8] + bv[2 + (v >> 2)][v & 3] + bf2f(b1[v]) + bf2f(c1[v]));
        }
        unsigned short* op = esyn + (size_t)e * H + cperm;
        *(u16x8*)op       = o0;
        *(u16x8*)(op + 8) = o1;
    }
}

// ------------- Kernel D1: per-block per-column partial sums (permuted cols) --
__global__ __launch_bounds__(256) void k_col_stats(const unsigned short* __restrict__ buf,
                                                   long nrows,
                                                   float* __restrict__ psum,
                                                   float* __restrict__ psq)
{
    const size_t total  = (size_t)nrows * (H / 8);
    const size_t stride = (size_t)gridDim.x * 256;     // multiple of 16
    float s[8], q[8];
#pragma unroll
    for (int j = 0; j < 8; j++) { s[j] = 0.f; q[j] = 0.f; }
    for (size_t i = (size_t)blockIdx.x * 256 + threadIdx.x; i < total; i += stride) {
        u16x8 v = ((const u16x8*)buf)[i];
#pragma unroll
        for (int j = 0; j < 8; j++) { float f = bf2f(v[j]); s[j] += f; q[j] += f * f; }
    }
    __shared__ float ls[256][8], lq[256][8];
#pragma unroll
    for (int j = 0; j < 8; j++) { ls[threadIdx.x][j] = s[j]; lq[threadIdx.x][j] = q[j]; }
    __syncthreads();
    if (threadIdx.x < 128) {
        const int c = threadIdx.x, cg = c >> 3, j = c & 7;
        float S = 0.f, Q = 0.f;
        for (int rg = 0; rg < 16; rg++) { S += ls[rg * 16 + cg][j]; Q += lq[rg * 16 + cg][j]; }
        psum[(size_t)blockIdx.x * H + c] = S;
        psq [(size_t)blockIdx.x * H + c] = Q;
    }
}

// ---------------- Kernel C: reduce partials -> scale/shift (permuted index) --
__global__ void k_bn_stats(const float* __restrict__ psum, const float* __restrict__ psq,
                           int nblk, float invN,
                           const float* __restrict__ gamma, const float* __restrict__ beta,
                           float* __restrict__ scale, float* __restrict__ shift)
{
    __shared__ float ls[256], lq[256];
    const int c = blockIdx.x;                 // permuted column index
    float s = 0.f, q = 0.f;
    for (int i = threadIdx.x; i < nblk; i += 256) {
        s += psum[(size_t)i * H + c];
        q += psq [(size_t)i * H + c];
    }
    ls[threadIdx.x] = s; lq[threadIdx.x] = q;
    __syncthreads();
    for (int off = 128; off > 0; off >>= 1) {
        if ((int)threadIdx.x < off) {
            ls[threadIdx.x] += ls[threadIdx.x + off];
            lq[threadIdx.x] += lq[threadIdx.x + off];
        }
        __syncthreads();
    }
    if (threadIdx.x == 0) {
        const int r = c & 31, kh = r >> 4, wi = r & 15;
        const int ct = (c & ~31) + (wi >> 2) * 8 + kh * 4 + (wi & 3);
        float mean = ls[0] * invN;
        float var  = lq[0] * invN - mean * mean;
        float sc   = gamma[ct] * rsqrtf(var + EPS);
        scale[c] = sc;
        shift[c] = beta[ct] - mean * sc;
    }
}

// ---------------- Kernel D2: bond finalize  esyn(bf16,perm) -> f32 true ------
__global__ __launch_bounds__(256) void k_bond_out(const unsigned short* __restrict__ esyn,
                                                  float* __restrict__ y,
                                                  const float* __restrict__ scale,
                                                  const float* __restrict__ shift)
{
    const size_t total  = (size_t)NB * (H / 8);
    const size_t stride = (size_t)gridDim.x * 256;
    const int c0 = (threadIdx.x & 15) * 8;
    const f32x4 sc0 = *(const f32x4*)(scale + c0), sc1 = *(const f32x4*)(scale + c0 + 4);
    const f32x4 sh0 = *(const f32x4*)(shift + c0), sh1 = *(const f32x4*)(shift + c0 + 4);
    const int tc0 = (c0 & ~31) + (((c0 >> 2) & 3) * 8) + ((c0 >> 4) & 1) * 4;
    const int tc1 = tc0 + 8;
    for (size_t i = (size_t)blockIdx.x * 256 + threadIdx.x; i < total; i += stride) {
        u16x8 v = ((const u16x8*)esyn)[i];
        const size_t row = i >> 4;
        f32x4 o0, o1;
#pragma unroll
        for (int j = 0; j < 4; j++) {
            o0[j] = fmaxf(bf2f(v[j])     * sc0[j] + sh0[j], 0.0f);
            o1[j] = fmaxf(bf2f(v[j + 4]) * sc1[j] + sh1[j], 0.0f);
        }
        float* yp = y + row * H;
        *(f32x4*)(yp + tc0) = o0;
        *(f32x4*)(yp + tc1) = o1;
    }
}

// -------- Kernel E: syn_a = (Ux+Ub) + sum_k sig(esyn[b])*(Vx[a]+Vb) ----------
__global__ __launch_bounds__(256) void k_atom_msg(
    const unsigned short* __restrict__ Ux,
    const unsigned short* __restrict__ Vx,
    const unsigned short* __restrict__ esyn,
    const int* __restrict__ adj,
    const int* __restrict__ abadj,
    const float* __restrict__ Ub, const float* __restrict__ Vb,
    unsigned short* __restrict__ syn_a,
    float* __restrict__ psum, float* __restrict__ psq)
{
    const int cg = threadIdx.x & 15;
    const int rh = threadIdx.x >> 4;
    const int c0 = cg * 8;                       // permuted chunk base
    const int tc0 = (c0 & ~31) + (((c0 >> 2) & 3) * 8) + ((c0 >> 4) & 1) * 4;
    // bias slices in permuted element order (v0..3 -> tc0+j, v4..7 -> tc0+8+j)
    const f32x4 ub0 = *(const f32x4*)(Ub + tc0), ub1 = *(const f32x4*)(Ub + tc0 + 8);
    const f32x4 vb0 = *(const f32x4*)(Vb + tc0), vb1 = *(const f32x4*)(Vb + tc0 + 8);

    float s[8], q[8];
#pragma unroll
    for (int j = 0; j < 8; j++) { s[j] = 0.f; q[j] = 0.f; }

    for (int r0 = blockIdx.x * 16; r0 < NA; r0 += gridDim.x * 16) {
        const int r = r0 + rh;
        u16x8 uv = *(const u16x8*)(Ux + (size_t)r * H + c0);
        float v[8];
#pragma unroll
        for (int j = 0; j < 4; j++) {
            v[j]     = bf2f(uv[j])     + ub0[j];
            v[j + 4] = bf2f(uv[j + 4]) + ub1[j];
        }
#pragma unroll
        for (int k = 0; k < 6; k++) {
            const int a = adj[r * 6 + k];
            const int b = abadj[r * 6 + k];
            u16x8 vx = *(const u16x8*)(Vx   + (size_t)a * H + c0);
            u16x8 es = *(const u16x8*)(esyn + (size_t)b * H + c0);
#pragma unroll
            for (int j = 0; j < 4; j++) {
                float g0 = 1.0f / (1.0f + __expf(-bf2f(es[j])));
                float g1 = 1.0f / (1.0f + __expf(-bf2f(es[j + 4])));
                v[j]     += g0 * (bf2f(vx[j])     + vb0[j]);
                v[j + 4] += g1 * (bf2f(vx[j + 4]) + vb1[j]);
            }
        }
        u16x8 ov;
#pragma unroll
        for (int j = 0; j < 8; j++) ov[j] = f2bf(v[j]);
        *(u16x8*)(syn_a + (size_t)r * H + c0) = ov;
#pragma unroll
        for (int j = 0; j < 8; j++) { s[j] += v[j]; q[j] += v[j] * v[j]; }
    }

    __shared__ float ls[256][8], lq[256][8];
#pragma unroll
    for (int j = 0; j < 8; j++) { ls[threadIdx.x][j] = s[j]; lq[threadIdx.x][j] = q[j]; }
    __syncthreads();
    if (threadIdx.x < 128) {
        const int c = threadIdx.x, g = c >> 3, j = c & 7;
        float S = 0.f, Q = 0.f;
        for (int rg = 0; rg < 16; rg++) { S += ls[rg * 16 + g][j]; Q += lq[rg * 16 + g][j]; }
        psum[(size_t)blockIdx.x * H + c] = S;
        psq [(size_t)blockIdx.x * H + c] = Q;
    }
}

// ---------------- Kernel F: atom finalize: bn(syn_a)+relu + residual ---------
__global__ __launch_bounds__(256) void k_atom_out(const unsigned short* __restrict__ syn,
                                                  const float* __restrict__ xin,
                                                  float* __restrict__ y,
                                                  const float* __restrict__ scale,
                                                  const float* __restrict__ shift)
{
    const size_t total  = (size_t)NA * (H / 8);
    const size_t stride = (size_t)gridDim.x * 256;
    const int c0 = (threadIdx.x & 15) * 8;
    const f32x4 sc0 = *(const f32x4*)(scale + c0), sc1 = *(const f32x4*)(scale + c0 + 4);
    const f32x4 sh0 = *(const f32x4*)(shift + c0), sh1 = *(const f32x4*)(shift + c0 + 4);
    const int tc0 = (c0 & ~31) + (((c0 >> 2) & 3) * 8) + ((c0 >> 4) & 1) * 4;
    const int tc1 = tc0 + 8;
    for (size_t i = (size_t)blockIdx.x * 256 + threadIdx.x; i < total; i += stride) {
        u16x8 v = ((const u16x8*)syn)[i];
        const size_t row = i >> 4;
        const float* xp = xin + row * H;
        f32x4 x0 = *(const f32x4*)(xp + tc0), x1 = *(const f32x4*)(xp + tc1);
        f32x4 o0, o1;
#pragma unroll
        for (int j = 0; j < 4; j++) {
            o0[j] = fmaxf(bf2f(v[j])     * sc0[j] + sh0[j], 0.0f) + x0[j];
            o1[j] = fmaxf(bf2f(v[j + 4]) * sc1[j] + sh1[j], 0.0f) + x1[j];
        }
        float* yp = y + row * H;
        *(f32x4*)(yp + tc0) = o0;
        *(f32x4*)(yp + tc1) = o1;
    }
}

extern "C" void kernel_launch(void* const* d_in, const int* in_sizes, int n_in,
                              void* d_out, int out_size, void* d_ws, size_t ws_size,
                              hipStream_t stream)
{
    const float* X     = (const float*)d_in[0];
    const float* Xb    = (const float*)d_in[1];
    const int*   adj   = (const int*)d_in[2];
    const int*   abadj = (const int*)d_in[3];
    const int*   g2    = (const int*)d_in[4];
    const float* Uw = (const float*)d_in[5],  *Ub = (const float*)d_in[6];
    const float* Vw = (const float*)d_in[7],  *Vb = (const float*)d_in[8];
    const float* Aw = (const float*)d_in[9],  *Ab = (const float*)d_in[10];
    const float* Bw = (const float*)d_in[11], *Bb = (const float*)d_in[12];
    const float* Cw = (const float*)d_in[13], *Cb = (const float*)d_in[14];
    const float* gb = (const float*)d_in[15], *bb = (const float*)d_in[16];
    const float* ga = (const float*)d_in[17], *ba = (const float*)d_in[18];

    float* out_atom = (float*)d_out;
    float* out_bond = out_atom + (size_t)NA * H;

    char* ws = (char*)d_ws;
    size_t o = 0;
    unsigned short* Ux    = (unsigned short*)(ws + o); o += (size_t)NA * H * 2;
    unsigned short* Vx    = (unsigned short*)(ws + o); o += (size_t)NA * H * 2;
    unsigned short* Bx    = (unsigned short*)(ws + o); o += (size_t)NA * H * 2;
    unsigned short* Cx    = (unsigned short*)(ws + o); o += (size_t)NA * H * 2;
    unsigned short* esyn  = (unsigned short*)(ws + o); o += (size_t)NB * H * 2;
    unsigned short* syn_a = (unsigned short*)(ws + o); o += (size_t)NA * H * 2;
    float* psum_b = (float*)(ws + o);  o += (size_t)EGRID * H * 4;
    float* psq_b  = (float*)(ws + o);  o += (size_t)EGRID * H * 4;
    float* psum_a = (float*)(ws + o);  o += (size_t)EGRID * H * 4;
    float* psq_a  = (float*)(ws + o);  o += (size_t)EGRID * H * 4;
    float* scale_b = (float*)(ws + o); o += 512;
    float* shift_b = (float*)(ws + o); o += 512;
    float* scale_a = (float*)(ws + o); o += 512;
    float* shift_a = (float*)(ws + o); o += 512;
    (void)o; (void)ws_size; (void)in_sizes; (void)n_in; (void)out_size;

    k_atom_gemm<<<GRID_A, 256, 0, stream>>>(X, Uw, Vw, Bw, Cw, Ux, Vx, Bx, Cx);
    k_bond_gemm<<<GRID_B, 256, 0, stream>>>(Xb, Aw, Ab, Bb, Cb, g2, Bx, Cx, esyn);
    k_col_stats<<<EGRID, 256, 0, stream>>>(esyn, NB, psum_b, psq_b);
    k_bn_stats<<<H, 256, 0, stream>>>(psum_b, psq_b, EGRID, 1.0f / NB, gb, bb, scale_b, shift_b);
    k_bond_out<<<EGRID, 256, 0, stream>>>(esyn, out_bond, scale_b, shift_b);
    k_atom_msg<<<EGRID, 256, 0, stream>>>(Ux, Vx, esyn, adj, abadj, Ub, Vb, syn_a, psum_a, psq_a);
    k_bn_stats<<<H, 256, 0, stream>>>(psum_a, psq_a, EGRID, 1.0f / NA, ga, ba, scale_a, shift_a);
    k_atom_out<<<EGRID, 256, 0, stream>>>(syn_a, X, out_atom, scale_a, shift_a);
}